// Round 5
// baseline (142.207 us; speedup 1.0000x reference)
//
#include <hip/hip_runtime.h>
#include <math.h>

// Match numpy's unfused f32 arithmetic (fma contraction shifts IoU at the
// 0.45 decision boundary). R1-R4 with this pragma matched absmax 0.0.
#pragma clang fp contract(off)

#define PNUM    3000
#define NTOT    4096                 // sort size: 4 keys/thread
#define NCLS    21
#define TOPK    200
#define BLOCK   1024
#define BATCH   256                  // candidates resolved per round
#define WIN     1024                 // decode window
#define NMS_T   0.45f
#define MAXKEEP (TOPK + BATCH)       // cnt<200 entering a round, +<=256 keeps

__device__ __forceinline__ float iou_f(float4 a, float aa, float4 b, float ab) {
    float ltx = fmaxf(a.x, b.x);
    float lty = fmaxf(a.y, b.y);
    float rbx = fminf(a.z, b.z);
    float rby = fminf(a.w, b.w);
    float iw  = fmaxf(rbx - ltx, 0.0f);
    float ih  = fmaxf(rby - lty, 0.0f);
    float inter = iw * ih;
    float uni   = aa + ab - inter;           // keeper area first (ref order)
    return inter / fmaxf(uni, 1e-12f);
}

// One block per (image b, class c). Full 4096-key register bitonic sort
// (4 keys/thread: shfl j<64, ping-pong LDS 64<=j<=512 [18 barriers],
// in-thread j>=1024) -> lazy greedy NMS in 256-candidate rounds:
// 4 threads/candidate check committed keeps + own one 64-bit in-batch
// suppression word; wave0 resolves the greedy recurrence sparsely in 4
// barrier-free sub-steps. 2 barriers/round. No thresholds, no refills:
// every block runs the identical data-independent structure.
__global__ __launch_bounds__(BLOCK) void ssd_nms_kernel(
    const float* __restrict__ loc,     // [B, PNUM, 4]
    const float* __restrict__ conf,    // [B, PNUM, NCLS]
    const float* __restrict__ priors,  // [PNUM, 4]
    float* __restrict__ out)           // [B, NCLS, TOPK, 5]
{
    const int c   = blockIdx.x;
    const int b   = blockIdx.y;
    const int tid = threadIdx.x;

    float* outbase = out + ((size_t)(b * NCLS + c)) * (TOPK * 5);

    if (c == 0) {
        for (int i = tid; i < TOPK * 5; i += BLOCK) outbase[i] = 0.0f;
        return;
    }

    __shared__ unsigned long long s_bufA[NTOT];     // 32 KB (holds final sorted keys)
    __shared__ unsigned long long s_bufB[NTOT];     // 32 KB sort pong
    __shared__ float4             s_box[WIN];       // 16 KB decode window
    __shared__ float              s_area[WIN];      // 4 KB
    __shared__ float              s_score[WIN];     // 4 KB
    __shared__ float4             s_kb[MAXKEEP];    // committed keep boxes
    __shared__ float              s_ka[MAXKEEP];
    __shared__ unsigned long long s_sup[BATCH][4];  // 8 KB in-batch suppression
    __shared__ unsigned long long s_dead[4];        // committed-keep dead bits
    __shared__ int                s_wcnt[16];
    __shared__ int s_cnt, s_done;

    const int lane = tid & 63;
    const int wav  = tid >> 6;

    // ---- build 4 sort keys/thread: element i = (q<<10)|tid ----
    unsigned long long e[4];
    const float* confb = conf + ((size_t)b * PNUM) * NCLS + c;
    int myv = 0;
    #pragma unroll
    for (int q = 0; q < 4; ++q) {
        int i = (q << 10) | tid;
        unsigned long long key = 0ull;
        if (i < PNUM) {
            float s = confb[(size_t)i * NCLS];
            if (s > 0.01f) {
                key = ((unsigned long long)__float_as_uint(s) << 32)
                    | (unsigned)(~i);
                myv++;
            }
        }
        e[q] = key;
    }
    for (int d = 32; d > 0; d >>= 1) myv += __shfl_down(myv, d);
    if (lane == 0) s_wcnt[wav] = myv;
    if (tid == 0) { s_cnt = 0; s_done = 0; }
    if (tid < 4)  s_dead[tid] = 0ull;
    // published by the sort's first LDS-stage barrier

    // ---- bitonic sort NTOT keys, descending (elementwise formula verified
    //      exact in R4: takeMax = ((i&j)==0)==((i&k)==0)) ----
    int parity = 0;
    for (unsigned k = 2; k <= NTOT; k <<= 1) {
        for (unsigned j = k >> 1; j > 0; j >>= 1) {
            if (j >= 1024) {
                int qj = (int)(j >> 10);              // 1 or 2
                #pragma unroll
                for (int qa = 0; qa < 4; ++qa) {
                    int qb = qa ^ qj;
                    if (qb > qa) {
                        unsigned ia = ((unsigned)qa << 10) | (unsigned)tid;
                        bool tm = ((ia & k) == 0);
                        unsigned long long A = e[qa], B = e[qb];
                        if ((B > A) == tm) { e[qa] = B; e[qb] = A; }
                    }
                }
            } else if (j >= 64) {
                unsigned long long* buf = parity ? s_bufB : s_bufA;
                #pragma unroll
                for (int q = 0; q < 4; ++q) buf[(q << 10) | tid] = e[q];
                __syncthreads();
                #pragma unroll
                for (int q = 0; q < 4; ++q) {
                    unsigned i = ((unsigned)q << 10) | (unsigned)tid;
                    unsigned long long pk = buf[i ^ j];
                    bool tm = (((i & j) == 0) == ((i & k) == 0));
                    if ((pk > e[q]) == tm) e[q] = pk;
                }
                parity ^= 1;
            } else {
                #pragma unroll
                for (int q = 0; q < 4; ++q) {
                    unsigned i = ((unsigned)q << 10) | (unsigned)tid;
                    unsigned long long pk = __shfl_xor(e[q], (int)j, 64);
                    bool tm = (((i & j) == 0) == ((i & k) == 0));
                    if ((pk > e[q]) == tm) e[q] = pk;
                }
            }
        }
    }
    // publish sorted keys
    #pragma unroll
    for (int q = 0; q < 4; ++q) s_bufA[(q << 10) | tid] = e[q];
    __syncthreads();

    int M = 0;
    #pragma unroll
    for (int w = 0; w < 16; ++w) M += s_wcnt[w];

    // ---- decode window [W, W+1024) ----
    auto decode_window = [&](int W) {
        int p = W + tid;
        if (p < M) {
            unsigned long long key = s_bufA[p];
            unsigned idx = ~(unsigned)key;
            float4 l  = ((const float4*)loc)[(size_t)b * PNUM + idx];
            float4 pr = ((const float4*)priors)[idx];
            float cx = pr.x + l.x * 0.1f * pr.z;
            float cy = pr.y + l.y * 0.1f * pr.w;
            float w  = pr.z * expf(l.z * 0.2f);
            float h  = pr.w * expf(l.w * 0.2f);
            float x1 = cx - 0.5f * w;
            float y1 = cy - 0.5f * h;
            float x2 = x1 + w;
            float y2 = y1 + h;
            s_box[tid]   = make_float4(x1, y1, x2, y2);
            s_area[tid]  = (x2 - x1) * (y2 - y1);
            s_score[tid] = __uint_as_float((unsigned)(key >> 32));
        }
        __syncthreads();
    };

    int W = 0;
    decode_window(0);

    // ---- lazy greedy rounds over sorted positions, BATCH at a time ----
    int pos = 0;
    while (pos < M) {
        if (pos >= W + WIN) { W += WIN; decode_window(W); }
        int bn  = M - pos; if (bn > BATCH) bn = BATCH;
        int cnt = s_cnt;                       // published at last barrier

        // phase 1 (all 1024 threads): 4 threads per candidate
        {
            int cid = tid & 255, g = tid >> 8;
            if (cid < bn) {
                int sl = (pos - W) + cid;
                float4 bL = s_box[sl];
                float  aL = s_area[sl];
                bool bad = false;
                for (int K = g; K < cnt; K += 4)
                    bad |= (iou_f(s_kb[K], s_ka[K], bL, aL) > NMS_T);
                if (bad) atomicOr(&s_dead[cid >> 6], 1ull << (cid & 63));
                unsigned long long bits = 0ull;
                int m0 = g << 6;
                int mEnd = cid < m0 + 64 ? cid : m0 + 64;   // Mi < cid
                for (int Mi = m0; Mi < mEnd; ++Mi) {
                    int slM = (pos - W) + Mi;
                    if (iou_f(s_box[slM], s_area[slM], bL, aL) > NMS_T)
                        bits |= 1ull << (Mi - m0);
                }
                s_sup[cid][g] = bits;          // exclusive owner, plain store
            }
        }
        __syncthreads();

        // phase 2: wave0 resolves greedy recurrence + emits keeps
        if (tid < 64) {
            unsigned long long S[4][4];
            #pragma unroll
            for (int sb = 0; sb < 4; ++sb) {
                int cd = (sb << 6) | lane;
                if (cd < bn) {
                    S[sb][0] = s_sup[cd][0]; S[sb][1] = s_sup[cd][1];
                    S[sb][2] = s_sup[cd][2]; S[sb][3] = s_sup[cd][3];
                } else {
                    S[sb][0] = S[sb][1] = S[sb][2] = S[sb][3] = 0ull;
                }
            }
            unsigned long long D0 = s_dead[0], D1 = s_dead[1],
                               D2 = s_dead[2], D3 = s_dead[3];
            unsigned long long K0 = 0, K1 = 0, K2 = 0, K3 = 0;

            #define SUBRESOLVE(SB, DW, KW, PRE)                                   \
            {                                                                     \
                unsigned long long own = S[SB][SB];                               \
                int cd = (SB << 6) | lane;                                        \
                bool alive = (cd < bn) && (((DW >> lane) & 1ull) == 0ull);        \
                unsigned long long pre = (PRE);                                   \
                KW |= __ballot(alive && pre == 0ull && own == 0ull);              \
                unsigned long long todo = __ballot(alive && pre != 0ull ? 0 : 0); \
                todo = __ballot(alive && pre == 0ull && own != 0ull);             \
                while (todo) {                                                    \
                    int L = __ffsll(todo) - 1;                                    \
                    unsigned long long ownL = __shfl(own, L, 64);                 \
                    if (!(ownL & KW)) KW |= 1ull << L;                            \
                    todo &= todo - 1;                                             \
                }                                                                 \
            }
            SUBRESOLVE(0, D0, K0, 0ull)
            SUBRESOLVE(1, D1, K1, (S[1][0] & K0))
            SUBRESOLVE(2, D2, K2, (S[2][0] & K0) | (S[2][1] & K1))
            SUBRESOLVE(3, D3, K3, (S[3][0] & K0) | (S[3][1] & K1) | (S[3][2] & K2))
            #undef SUBRESOLVE

            int n0 = (int)__popcll(K0), n1 = (int)__popcll(K1),
                n2 = (int)__popcll(K2), n3 = (int)__popcll(K3);
            int keptN = n0 + n1 + n2 + n3;
            #pragma unroll
            for (int sb = 0; sb < 4; ++sb) {
                unsigned long long KW = sb == 0 ? K0 : sb == 1 ? K1 : sb == 2 ? K2 : K3;
                if ((KW >> lane) & 1ull) {
                    int base  = sb == 0 ? 0 : sb == 1 ? n0 : sb == 2 ? n0 + n1 : n0 + n1 + n2;
                    int krank = base + (int)__popcll(KW & ((1ull << lane) - 1ull));
                    int cd  = (sb << 6) | lane;
                    int sl2 = (pos - W) + cd;
                    int kid = cnt + krank;               // < MAXKEEP
                    float4 bx = s_box[sl2];
                    s_kb[kid] = bx;
                    s_ka[kid] = s_area[sl2];
                    if (kid < TOPK) {
                        float* o = outbase + (size_t)kid * 5;
                        o[0] = s_score[sl2];
                        o[1] = bx.x; o[2] = bx.y; o[3] = bx.z; o[4] = bx.w;
                    }
                }
            }
            if (lane == 0) {
                s_dead[0] = 0ull; s_dead[1] = 0ull;
                s_dead[2] = 0ull; s_dead[3] = 0ull;
                s_cnt  = cnt + keptN;
                s_done = (cnt + keptN >= TOPK) ? 1 : 0;
            }
        }
        __syncthreads();
        if (s_done) break;                     // first TOPK rows fixed
        pos += bn;
    }

    // ---- zero unwritten tail rows ----
    const int cf = s_cnt < TOPK ? s_cnt : TOPK;
    for (int r = cf + tid; r < TOPK; r += BLOCK) {
        float* o = outbase + (size_t)r * 5;
        o[0] = 0.f; o[1] = 0.f; o[2] = 0.f; o[3] = 0.f; o[4] = 0.f;
    }
}

extern "C" void kernel_launch(void* const* d_in, const int* in_sizes, int n_in,
                              void* d_out, int out_size, void* d_ws, size_t ws_size,
                              hipStream_t stream) {
    const float* loc    = (const float*)d_in[0];
    const float* conf   = (const float*)d_in[1];
    const float* priors = (const float*)d_in[2];
    float* out          = (float*)d_out;
    const int B = in_sizes[0] / (PNUM * 4);   // 8
    dim3 grid(NCLS, B);
    ssd_nms_kernel<<<grid, BLOCK, 0, stream>>>(loc, conf, priors, out);
}

// Round 6
// 113.525 us; speedup vs baseline: 1.2526x; 1.2526x over previous
//
#include <hip/hip_runtime.h>
#include <math.h>

// Match numpy's unfused f32 arithmetic (fma contraction shifts IoU at the
// 0.45 decision boundary). R1-R5 with this pragma matched absmax 0.0.
#pragma clang fp contract(off)

#define PNUM    3000
#define NCLS    21
#define TOPK    200
#define BLOCK   1024
#define CHUNK   1024
#define NMS_T   0.45f
#define LO_BITS 0x3C23D70Bu          // smallest float bits strictly > 0.01f
#define HI_BITS 0x3F800001u          // > bits of any score in [0,1]
#define MAXKEEP (TOPK + 64)

__device__ __forceinline__ float iou_f(float4 a, float aa, float4 b, float ab) {
    float ltx = fmaxf(a.x, b.x);
    float lty = fmaxf(a.y, b.y);
    float rbx = fminf(a.z, b.z);
    float rby = fminf(a.w, b.w);
    float iw  = fmaxf(rbx - ltx, 0.0f);
    float ih  = fmaxf(rby - lty, 0.0f);
    float inter = iw * ih;
    float uni   = aa + ab - inter;           // keeper area first (ref order)
    return inter / fmaxf(uni, 1e-12f);
}

// One block per (image b, class c). R4 structure (62 us) with the refill
// bisection replaced by a FIXED threshold ladder (0.70/0.40/0.10/0.01+):
// each rung holds ~900 of the ~2970 uniform scores, so count<=1024 always on
// this data; a bisection fallback keeps worst-case exact. Count+compact fused
// via per-wave ballot counts + wave-prefix bases: 2 barriers, no atomics.
// Then: 1024-key register bitonic sort (shfl j<64, ping-pong LDS j>=64 = 10
// barriers), decode, lazy greedy NMS in 64-candidate rounds (2 barriers each).
__global__ __launch_bounds__(BLOCK) void ssd_nms_kernel(
    const float* __restrict__ loc,     // [B, PNUM, 4]
    const float* __restrict__ conf,    // [B, PNUM, NCLS]
    const float* __restrict__ priors,  // [PNUM, 4]
    float* __restrict__ out)           // [B, NCLS, TOPK, 5]
{
    const int c   = blockIdx.x;
    const int b   = blockIdx.y;
    const int tid = threadIdx.x;

    float* outbase = out + ((size_t)(b * NCLS + c)) * (TOPK * 5);

    if (c == 0) {
        for (int i = tid; i < TOPK * 5; i += BLOCK) outbase[i] = 0.0f;
        return;
    }

    __shared__ unsigned long long s_bufA[CHUNK];  // 8 KB  sort ping
    __shared__ unsigned long long s_bufB[CHUNK];  // 8 KB  sort pong
    __shared__ float4             s_box[CHUNK];   // 16 KB decoded chunk boxes
    __shared__ float              s_area[CHUNK];  // 4 KB
    __shared__ float              s_score[CHUNK]; // 4 KB
    __shared__ float4             s_kb[MAXKEEP];  // committed keep boxes
    __shared__ float              s_ka[MAXKEEP];
    __shared__ unsigned long long s_supp[64];     // in-batch suppression bits
    __shared__ int                s_supc[64];     // suppressed-by-committed flag
    __shared__ int                s_wcnt[16];     // per-wave candidate counts
    __shared__ int s_cnt, s_done;

    const int lane = tid & 63;
    const int wav  = tid >> 6;

    // ---- per-thread score bits in registers (elements tid + q*1024) ----
    unsigned hb[4];
    const float* confb = conf + ((size_t)b * PNUM) * NCLS + c;
    #pragma unroll
    for (int q = 0; q < 4; ++q) {
        int i = tid + (q << 10);
        unsigned h = 0u;
        if (i < PNUM) {
            float s = confb[(size_t)i * NCLS];
            if (s > 0.01f) h = __float_as_uint(s);
        }
        hb[q] = h;
    }
    if (tid < 64) { s_supp[lane] = 0ull; s_supc[lane] = 0; }
    if (tid == 0) { s_cnt = 0; s_done = 0; }
    // (published by the first count barrier below)

    unsigned Thi = HI_BITS;
    bool done = false;

    for (;;) {   // ================= chunk loop =================
        // next ladder rung strictly below Thi
        unsigned T = (0x3F333333u < Thi) ? 0x3F333333u      // 0.70f
                   : (0x3ECCCCCDu < Thi) ? 0x3ECCCCCDu      // 0.40f
                   : (0x3DCCCCCDu < Thi) ? 0x3DCCCCCDu      // 0.10f
                   : LO_BITS;

        // ---- count pass (per-wave ballots; 2 barriers), rare bisect fallback ----
        int M, wbase;
        for (;;) {
            __syncthreads();   // protect s_wcnt / s_bufA reuse from prior phase
            int wc = 0;
            #pragma unroll
            for (int q = 0; q < 4; ++q) {
                bool p = (hb[q] >= T && hb[q] < Thi);
                wc += (int)__popcll(__ballot(p));
            }
            if (lane == 0) s_wcnt[wav] = wc;
            s_bufA[tid] = 0ull;            // pad keys sort last (desc)
            __syncthreads();
            M = 0; wbase = 0;
            #pragma unroll
            for (int w = 0; w < 16; ++w) {
                int v = s_wcnt[w];
                M += v;
                if (w < wav) wbase += v;
            }
            if (M <= CHUNK) break;
            // fallback: smallest T' in (T, Thi] with count <= CHUNK
            unsigned lo = T + 1, hi = Thi;
            while (lo < hi) {
                unsigned mid = lo + ((hi - lo) >> 1);
                __syncthreads();
                int c2 = 0;
                #pragma unroll
                for (int q = 0; q < 4; ++q)
                    c2 += (int)__popcll(__ballot(hb[q] >= mid && hb[q] < Thi));
                if (lane == 0) s_wcnt[wav] = c2;
                __syncthreads();
                int n = 0;
                #pragma unroll
                for (int w = 0; w < 16; ++w) n += s_wcnt[w];
                if (n <= CHUNK) hi = mid; else lo = mid + 1;
            }
            T = hi;                        // recount + rezero with final T
        }

        if (M == 0) {
            if (T <= LO_BITS) break;       // nothing left at all
            Thi = T;                       // empty rung: descend
            continue;
        }

        // ---- compact [T, Thi) into s_bufA, no atomics (wave-prefix bases) ----
        {
            int base = wbase;
            #pragma unroll
            for (int q = 0; q < 4; ++q) {
                unsigned sb = hb[q];
                bool p = (sb >= T && sb < Thi);
                unsigned long long bal = __ballot(p);
                if (p) {
                    int dst = base + (int)__popcll(bal & ((1ull << lane) - 1ull));
                    int i = tid + (q << 10);
                    s_bufA[dst] = ((unsigned long long)sb << 32) | (unsigned)(~i);
                }
                base += (int)__popcll(bal);
            }
        }
        __syncthreads();

        // ---- register bitonic sort, descending; shfl_xor for j<64,
        //      ping-pong LDS exchange (1 barrier each) for j>=64 ----
        unsigned long long key = s_bufA[tid];
        int parity = 0;
        for (unsigned k = 2; k <= CHUNK; k <<= 1) {
            for (unsigned j = k >> 1; j > 0; j >>= 1) {
                unsigned long long pk;
                if (j >= 64) {
                    unsigned long long* buf = parity ? s_bufB : s_bufA;
                    buf[tid] = key;
                    __syncthreads();
                    pk = buf[tid ^ j];
                    parity ^= 1;
                } else {
                    pk = __shfl_xor(key, (int)j, 64);
                }
                bool takeMax  = (((tid & j) == 0) == ((tid & k) == 0));
                bool pGreater = pk > key;
                if (takeMax == pGreater) key = pk;
            }
        }

        // ---- decode chunk boxes (thread tid == sorted rank tid) ----
        if (key != 0ull) {
            unsigned idx = ~(unsigned)key;        // original prior index
            float4 l  = ((const float4*)loc)[(size_t)b * PNUM + idx];
            float4 pr = ((const float4*)priors)[idx];
            float cx = pr.x + l.x * 0.1f * pr.z;
            float cy = pr.y + l.y * 0.1f * pr.w;
            float w  = pr.z * expf(l.z * 0.2f);
            float h  = pr.w * expf(l.w * 0.2f);
            float x1 = cx - 0.5f * w;
            float y1 = cy - 0.5f * h;
            float x2 = x1 + w;
            float y2 = y1 + h;
            s_box[tid]   = make_float4(x1, y1, x2, y2);
            s_area[tid]  = (x2 - x1) * (y2 - y1);
            s_score[tid] = __uint_as_float((unsigned)(key >> 32));
        }
        __syncthreads();

        // ---- lazy greedy rounds: 64 sorted positions per round ----
        int pos = 0;
        while (pos < M) {
            int bn  = M - pos; if (bn > 64) bn = 64;
            int cnt = s_cnt;                      // published at last barrier

            // CK: all 16 waves check candidates vs committed keeps + in-batch
            if (lane < bn) {
                float4 bL = s_box[pos + lane];
                float  aL = s_area[pos + lane];
                for (int K = wav; K < cnt; K += 16) {
                    if (iou_f(s_kb[K], s_ka[K], bL, aL) > NMS_T) {
                        atomicOr(&s_supc[lane], 1);
                        break;
                    }
                }
                unsigned long long bits = 0ull;
                int M0 = wav << 2;
                #pragma unroll
                for (int q2 = 0; q2 < 4; ++q2) {
                    int Mi = M0 + q2;
                    if (Mi < lane) {
                        if (iou_f(s_box[pos + Mi], s_area[pos + Mi], bL, aL) > NMS_T)
                            bits |= (1ull << Mi);
                    }
                }
                if (bits) atomicOr(&s_supp[lane], bits);
            }
            __syncthreads();

            // D: wave0 resolves greedy recurrence, emits rows, appends keeps
            if (tid < 64) {
                unsigned long long sup      = s_supp[lane];
                unsigned long long deadmask = __ballot(s_supc[lane] != 0);
                unsigned long long kept     = 0ull;
                for (int Mi = 0; Mi < bn; ++Mi) {
                    unsigned long long supM = __shfl(sup, Mi, 64);
                    if (!((deadmask >> Mi) & 1ull) && !(supM & kept))
                        kept |= (1ull << Mi);
                }
                int keptN = (int)__popcll(kept);
                bool me   = (lane < bn) && ((kept >> lane) & 1ull);
                int krank = (int)__popcll(kept & ((1ull << lane) - 1ull));
                if (me) {
                    int kid = cnt + krank;        // < MAXKEEP by construction
                    float4 bx = s_box[pos + lane];
                    s_kb[kid] = bx;
                    s_ka[kid] = s_area[pos + lane];
                    if (kid < TOPK) {
                        float* o = outbase + (size_t)kid * 5;
                        o[0] = s_score[pos + lane];
                        o[1] = bx.x; o[2] = bx.y; o[3] = bx.z; o[4] = bx.w;
                    }
                }
                s_supp[lane] = 0ull;              // reset for next round
                s_supc[lane] = 0;
                if (lane == 0) {
                    s_cnt  = cnt + keptN;
                    s_done = (cnt + keptN >= TOPK) ? 1 : 0;
                }
            }
            __syncthreads();
            if (s_done) { done = true; break; }   // first TOPK rows fixed
            pos += bn;
        }

        if (done) break;
        if (T <= LO_BITS) break;                  // all candidates consumed
        Thi = T;                                  // next chunk: scores in [?, T)
    }

    // ---- zero unwritten tail rows ----
    const int cf = s_cnt < TOPK ? s_cnt : TOPK;
    for (int r = cf + tid; r < TOPK; r += BLOCK) {
        float* o = outbase + (size_t)r * 5;
        o[0] = 0.f; o[1] = 0.f; o[2] = 0.f; o[3] = 0.f; o[4] = 0.f;
    }
}

extern "C" void kernel_launch(void* const* d_in, const int* in_sizes, int n_in,
                              void* d_out, int out_size, void* d_ws, size_t ws_size,
                              hipStream_t stream) {
    const float* loc    = (const float*)d_in[0];
    const float* conf   = (const float*)d_in[1];
    const float* priors = (const float*)d_in[2];
    float* out          = (float*)d_out;
    const int B = in_sizes[0] / (PNUM * 4);   // 8
    dim3 grid(NCLS, B);
    ssd_nms_kernel<<<grid, BLOCK, 0, stream>>>(loc, conf, priors, out);
}